// Round 15
// baseline (578.373 us; speedup 1.0000x reference)
//
#include <hip/hip_runtime.h>
#include <stdint.h>

// Problem constants
#define B_    8
#define T_    4096
#define HID   512
#define SD    256
#define NH    8
#define HD    32
#define M_TOK (B_*T_)          // 32768 tokens

typedef __attribute__((ext_vector_type(8))) short short8;   // 8 bf16 (4 VGPRs) — MFMA A/B frag
typedef __attribute__((ext_vector_type(4))) float f32x4;    // MFMA C/D frag
typedef __attribute__((ext_vector_type(4))) float f4;       // reg-tuple 4xf32 (asm-safe)
typedef __attribute__((ext_vector_type(2))) float f2;       // packed fp32 (v_pk_*_f32)

__device__ __forceinline__ unsigned short f2bf(float f) {
  uint32_t u = __float_as_uint(f);
  uint32_t r = (u + 0x7fffu + ((u >> 16) & 1u)) >> 16;
  return (unsigned short)r;
}

__device__ __forceinline__ void gload16(const void* g, void* l) {
  // async global->LDS, 16B per lane; LDS dest = wave-uniform base + lane*16
  __builtin_amdgcn_global_load_lds((const __attribute__((address_space(1))) void*)g,
                                   (__attribute__((address_space(3))) void*)l,
                                   16, 0, 0);
}

// butterfly sum across 16 consecutive lanes — pure VALU (DPP), no DS pipe.
__device__ __forceinline__ float qred16(float x) {
  x += __int_as_float(__builtin_amdgcn_mov_dpp(__float_as_int(x), 0xB1,  0xF, 0xF, true));
  x += __int_as_float(__builtin_amdgcn_mov_dpp(__float_as_int(x), 0x4E,  0xF, 0xF, true));
  x += __int_as_float(__builtin_amdgcn_mov_dpp(__float_as_int(x), 0x141, 0xF, 0xF, true));
  x += __int_as_float(__builtin_amdgcn_mov_dpp(__float_as_int(x), 0x128, 0xF, 0xF, true));
  return x;
}

// value of lane^1 (quad_perm [1,0,3,2]) — pure VALU
__device__ __forceinline__ float dpp_xor1(float x) {
  return __int_as_float(__builtin_amdgcn_mov_dpp(__float_as_int(x), 0xB1, 0xF, 0xF, true));
}

// ---------------------------------------------------------------- converts
__global__ void cvt_f32_bf16(const float* __restrict__ in, unsigned short* __restrict__ out, int n4) {
  int i = blockIdx.x * blockDim.x + threadIdx.x;
  int stride = gridDim.x * blockDim.x;
  for (; i < n4; i += stride) {
    float4 v = reinterpret_cast<const float4*>(in)[i];
    ushort4 o;
    o.x = f2bf(v.x); o.y = f2bf(v.y); o.z = f2bf(v.z); o.w = f2bf(v.w);
    reinterpret_cast<ushort4*>(out)[i] = o;
  }
}

// all 7 weight matrices in one launch: grid (128, 7), 32768 float4 per slice
__global__ void __launch_bounds__(256) cvt_weights(
    const float* __restrict__ W_k, const float* __restrict__ W_v,
    const float* __restrict__ W_q, const float* __restrict__ W_beta,
    const float* __restrict__ W_alpha, const float* __restrict__ gate_W,
    const float* __restrict__ W_out,
    unsigned short* __restrict__ Wc, unsigned short* __restrict__ Wob)
{
  int slice = blockIdx.y;
  const float* src = (slice == 0) ? W_k : (slice == 1) ? W_v : (slice == 2) ? W_q :
                     (slice == 3) ? W_beta : (slice == 4) ? W_alpha : (slice == 5) ? gate_W : W_out;
  unsigned short* dst = (slice == 6) ? Wob : (Wc + slice * 131072);
  int i = blockIdx.x * 256 + threadIdx.x;   // 0..32767 float4 units
  float4 v = reinterpret_cast<const float4*>(src)[i];
  ushort4 o;
  o.x = f2bf(v.x); o.y = f2bf(v.y); o.z = f2bf(v.z); o.w = f2bf(v.w);
  reinterpret_cast<ushort4*>(dst)[i] = o;
}

// ---------------------------------------------------------------- projection GEMM (fused 3-way)
// grid (256, 8): role 0-3: col-tile of {k, q, gate}; role 4-7: {alpha, v, beta}.
// KQi layout: [tok][16 groups g][k_{2g} k_{2g+1} q_{2g} q_{2g+1}] (16B/group).
// Epilogue writes FULL 16B groups per store (KQi via lane^1 DPP pair-exchange,
// even lanes store float4 {k0,k1,q0,q1}; AVB one float4 {a,v,b,0} per lane).
// k-normalization fused in-register (16-lane qred16 per token-half).
#define PM 128
#define PN 64
#define PK 64

__global__ void __launch_bounds__(256) proj_gemm(
    const unsigned short* __restrict__ hb, const unsigned short* __restrict__ Wc,
    const float* __restrict__ b_beta, const float* __restrict__ b_alpha,
    float* __restrict__ KQi, float* __restrict__ AVBf, float* __restrict__ gate)
{
  __shared__ unsigned short Asm[PM*PK];      // 16 KB
  __shared__ unsigned short Bsm[3][PN*PK];   // 24 KB
  const int t = threadIdx.x;
  const int w = t >> 6, lane = t & 63;
  const int bm0 = blockIdx.x * PM;
  const int role = blockIdx.y;
  const int grp = role >> 2;       // 0 = {k,q,gate}, 1 = {alpha,v,beta}
  const int bn0 = (role & 3) * 64; // column offset within each projection (0..255)
  const int pr0 = grp ? 4 : 0, pr1 = grp ? 1 : 2, pr2 = grp ? 3 : 5;

  f32x4 acc[3][2][4];
  #pragma unroll
  for (int pp = 0; pp < 3; ++pp)
    #pragma unroll
    for (int i = 0; i < 2; ++i)
      #pragma unroll
      for (int j = 0; j < 4; ++j) acc[pp][i][j] = (f32x4){0.f, 0.f, 0.f, 0.f};

  for (int k0 = 0; k0 < HID; k0 += PK) {
    #pragma unroll
    for (int it = 0; it < 4; ++it) {
      int unit = t + it * 256;
      int row = unit >> 3, seg = unit & 7;
      int dseg = seg ^ (row & 7);
      const unsigned short* g = hb + (size_t)(bm0 + row) * HID + k0 + dseg * 8;
      gload16(g, (char*)Asm + (w * 1024 + it * 4096));
    }
    #pragma unroll
    for (int pp = 0; pp < 3; ++pp) {
      const int pr = (pp == 0) ? pr0 : (pp == 1) ? pr1 : pr2;
      #pragma unroll
      for (int it = 0; it < 2; ++it) {
        int unit = t + it * 256;
        int n = unit >> 3, seg = unit & 7;
        int dseg = seg ^ (n & 7);
        const unsigned short* g = Wc + (size_t)(pr * 256 + bn0 + n) * HID + k0 + dseg * 8;
        gload16(g, (char*)Bsm[pp] + (w * 1024 + it * 4096));
      }
    }
    __syncthreads();
    #pragma unroll
    for (int ks = 0; ks < 2; ++ks) {
      short8 af[2];
      int u = ks * 4 + (lane >> 4);
      int slot = u ^ (lane & 7);
      #pragma unroll
      for (int rb = 0; rb < 2; ++rb) {
        int row = w * 32 + rb * 16 + (lane & 15);
        af[rb] = *(const short8*)((const char*)Asm + row * 128 + slot * 16);
      }
      #pragma unroll
      for (int pp = 0; pp < 3; ++pp) {
        short8 bfr[4];
        #pragma unroll
        for (int cb = 0; cb < 4; ++cb) {
          int nn = cb * 16 + (lane & 15);
          bfr[cb] = *(const short8*)((const char*)Bsm[pp] + nn * 128 + slot * 16);
        }
        #pragma unroll
        for (int rb = 0; rb < 2; ++rb)
          #pragma unroll
          for (int cb = 0; cb < 4; ++cb)
            acc[pp][rb][cb] = __builtin_amdgcn_mfma_f32_16x16x32_bf16(af[rb], bfr[cb], acc[pp][rb][cb], 0, 0, 0);
      }
    }
    __syncthreads();
  }

  if (grp == 0) {
    // fused k-normalization (16-lane DPP row covers all 32 d of one (m,h))
    #pragma unroll
    for (int rb = 0; rb < 2; ++rb) {
      #pragma unroll
      for (int r = 0; r < 4; ++r) {
        float s0 = acc[0][rb][0][r] * acc[0][rb][0][r] + acc[0][rb][1][r] * acc[0][rb][1][r];
        float s1 = acc[0][rb][2][r] * acc[0][rb][2][r] + acc[0][rb][3][r] * acc[0][rb][3][r];
        s0 = qred16(s0); s1 = qred16(s1);
        float i0 = 1.0f / fmaxf(sqrtf(s0), 1e-12f);
        float i1 = 1.0f / fmaxf(sqrtf(s1), 1e-12f);
        acc[0][rb][0][r] *= i0; acc[0][rb][1][r] *= i0;
        acc[0][rb][2][r] *= i1; acc[0][rb][3][r] *= i1;
      }
    }
    // even lanes write full KQi 16B group {k0,k1,q0,q1}
    #pragma unroll
    for (int rb = 0; rb < 2; ++rb) {
      #pragma unroll
      for (int cb = 0; cb < 4; ++cb) {
        int rem = bn0 + cb * 16 + (lane & 15);
        int h = rem >> 5, d = rem & 31;
        #pragma unroll
        for (int r = 0; r < 4; ++r) {
          int m = bm0 + w * 32 + rb * 16 + (lane >> 4) * 4 + r;
          int bb = m >> 12, tt = m & 4095;
          size_t tok = ((size_t)(bb * NH + h) * T_ + tt);
          float kv = acc[0][rb][cb][r], qv = acc[1][rb][cb][r];
          float kn = dpp_xor1(kv), qn = dpp_xor1(qv);
          if ((lane & 1) == 0)
            *(float4*)&KQi[tok * 64 + (d >> 1) * 4] = (float4){kv, kn, qv, qn};
          gate[(size_t)m * SD + rem] = acc[2][rb][cb][r];
        }
      }
    }
  } else {
    // one full 16B AVB group {alpha, v, beta, 0} per lane
    #pragma unroll
    for (int rb = 0; rb < 2; ++rb) {
      #pragma unroll
      for (int cb = 0; cb < 4; ++cb) {
        int rem = bn0 + cb * 16 + (lane & 15);
        int h = rem >> 5, d = rem & 31;
        #pragma unroll
        for (int r = 0; r < 4; ++r) {
          int m = bm0 + w * 32 + rb * 16 + (lane >> 4) * 4 + r;
          int bb = m >> 12, tt = m & 4095;
          size_t tok = ((size_t)(bb * NH + h) * T_ + tt);
          float av = 1.0f / (1.0f + expf(-(acc[0][rb][cb][r] + b_alpha[rem])));
          float vv = acc[1][rb][cb][r];
          float bv = 1.0f / (1.0f + expf(-(acc[2][rb][cb][r] + b_beta[rem])));
          *(float4*)&AVBf[(tok * HD + d) * 4] = (float4){av, vv, bv, 0.0f};
        }
      }
    }
  }
}

// ---------------------------------------------------------------- sequential scan
// 512 blocks x 64 threads (1 wave, NO LDS, NO barriers). block = (rg, bh):
// bh = blk&63 (same-XCD for all 8 rg of a bh), rg = blk>>6. Lane = row il
// (lw>>4) x part p (lw&15), 2 state cols/lane (one f2).
// 2-step lookahead pairs: W0 = S.k_t, W1 = S.k_{t+1}, G = k_t.k_{t+1} — THREE
// parallel qred16 DPP chains; u1 = c1 - c2*u0 with c2 = b1 a1 G. Readout
// qred16s off-chain, lane-selected, 1 global dword store per 16 steps.
// Inputs read DIRECTLY from global (L2-resident, coalesced 16B/lane) via
// order-pinned inline-asm global_load_dwordx4. Depth-4 pair pipeline: 16
// loads outstanding, steady s_waitcnt vmcnt(12) (exact: 3 newer pair-sets =
// 12 loads; in-flight ctx stores only make the wait conservative).
#define NPAIR (T_/2)

#define GLDO(dst, ptr, imm) \
  asm volatile("global_load_dwordx4 %0, %1, off offset:%c2" : "=v"(dst) : "v"(ptr), "i"(imm))

#define STG(ptr, val) \
  asm volatile("global_store_dword %0, %1, off" :: "v"(ptr), "v"(val) : "memory")

#define SHUF2(V,A,B) __builtin_shufflevector(V, V, A, B)

__global__ void __launch_bounds__(64, 1) scan_kernel(
    const float* __restrict__ KQi, const float* __restrict__ AVBf,
    const float* __restrict__ state_in,
    float* __restrict__ ctx, float* __restrict__ Sfin)
{
  const int blk = blockIdx.x;
  const int bh = blk & 63, rg = blk >> 6;
  const int b = bh >> 3, h = bh & 7;
  const int lw = threadIdx.x;
  const int il = lw >> 4;    // local row 0..3 (global row rg*4+il)
  const int p  = lw & 15;    // column part (cols 2p, 2p+1)

  const float* kp = KQi  + (size_t)bh * (T_ * 64) + p * 4;              // + t*64
  const float* vp = AVBf + (size_t)bh * (T_ * 128) + (rg * 4 + il) * 4; // + t*128

  f2 S2;
  {
    const float* sp = state_in + (size_t)bh * 1024 + (rg * 4 + il) * 32 + p * 2;
    S2 = (f2){sp[0], sp[1]};
  }

  float osel = 0.0f;
  float* ctxp = ctx + (size_t)b * T_ * SD + (size_t)p * SD + h * HD + rg * 4 + il;

  // 4 pair-sets in flight: (A,B) (C,D) (E,F) (G,H)
  f4 kqA, vvA, kqB, vvB, kqC, vvC, kqD, vvD;
  f4 kqE, vvE, kqF, vvF, kqG, vvG, kqH, vvH;

#define R2G(X, Y) do { \
    GLDO(kq##X, kp, 0); \
    GLDO(vv##X, vp, 0); \
    GLDO(kq##Y, kp, 256); \
    GLDO(vv##Y, vp, 512); \
    kp += 128; vp += 256; \
  } while (0)

#define WV(N, X, Y) \
    asm volatile("s_waitcnt vmcnt(" #N ")" \
                 : "+v"(kq##X), "+v"(vv##X), "+v"(kq##Y), "+v"(vv##Y))

// pair compute: X = even step T0, Y = T0+1. Three parallel qred16 chains
// (W0, W1, G); readout qred16s off the recurrence chain.
#define C2(X, Y, T0) do { \
    f2 k0_ = SHUF2(kq##X, 0, 1), q0_ = SHUF2(kq##X, 2, 3); \
    f2 k1_ = SHUF2(kq##Y, 0, 1), q1_ = SHUF2(kq##Y, 2, 3); \
    f4 VA_ = vv##X, VB_ = vv##Y; \
    f2 dA_ = k0_ * S2, dB_ = k1_ * S2, dG_ = k0_ * k1_; \
    float W0_ = qred16(dA_.x + dA_.y); \
    float W1_ = qred16(dB_.x + dB_.y); \
    float G_  = qred16(dG_.x + dG_.y); \
    float u0_ = fmaf(-(VA_.z * VA_.x), W0_, VA_.z * VA_.y); \
    float bua_ = VB_.z * VB_.x; \
    float c2_ = bua_ * G_; \
    float c1_ = fmaf(-(bua_ * VA_.x), W1_, VB_.z * VB_.y); \
    float u1_ = fmaf(-c2_, u0_, c1_); \
    f2 St_ = __builtin_elementwise_fma((f2){u0_, u0_}, k0_, (f2){VA_.x, VA_.x} * S2); \
    f2 Su_ = __builtin_elementwise_fma((f2){u1_, u1_}, k1_, (f2){VB_.x, VB_.x} * St_); \
    f2 o0_ = q0_ * St_; \
    f2 o1_ = q1_ * Su_; \
    S2 = Su_; \
    float od0_ = qred16(o0_.x + o0_.y); \
    float od1_ = qred16(o1_.x + o1_.y); \
    osel = (p == ((T0) & 15))       ? od0_ : osel; \
    osel = (p == (((T0) + 1) & 15)) ? od1_ : osel; \
    if ((((T0) + 1) & 15) == 15) { STG(ctxp, osel); ctxp += 16 * SD; } \
  } while (0)

  // prologue: 4 pair-sets in flight (16 loads)
  R2G(A,B); R2G(C,D); R2G(E,F); R2G(G,H);

  // main loop: 255 iterations x 8 pairs = pairs 0..2039 (prefetch to 2043)
  #pragma unroll 1
  for (int it = 0; it < (NPAIR - 8) / 8; ++it) {
    WV(12,A,B); C2(A,B, 0); R2G(A,B);
    WV(12,C,D); C2(C,D, 2); R2G(C,D);
    WV(12,E,F); C2(E,F, 4); R2G(E,F);
    WV(12,G,H); C2(G,H, 6); R2G(G,H);
    WV(12,A,B); C2(A,B, 8); R2G(A,B);
    WV(12,C,D); C2(C,D,10); R2G(C,D);
    WV(12,E,F); C2(E,F,12); R2G(E,F);
    WV(12,G,H); C2(G,H,14); R2G(G,H);
  }
  // epilogue: pairs 2040..2047 (prefetch 2044..2047, then drain)
  WV(12,A,B); C2(A,B, 0); R2G(A,B);
  WV(12,C,D); C2(C,D, 2); R2G(C,D);
  WV(12,E,F); C2(E,F, 4); R2G(E,F);
  WV(12,G,H); C2(G,H, 6); R2G(G,H);
  WV(12,A,B); C2(A,B, 8);
  WV(8 ,C,D); C2(C,D,10);
  WV(4 ,E,F); C2(E,F,12);
  WV(0 ,G,H); C2(G,H,14);

  {
    float* sp = Sfin + (size_t)bh * 1024 + (rg * 4 + il) * 32 + p * 2;
    sp[0] = S2.x; sp[1] = S2.y;
  }
#undef C2
#undef R2G
#undef WV
}

// ---------------------------------------------------------------- rmsnorm * silu(gate) -> bf16
__global__ void __launch_bounds__(256) rms_silu(
    const float* __restrict__ ctx, const float* __restrict__ gate,
    const float* __restrict__ norm_w, unsigned short* __restrict__ ctx2)
{
  size_t row = (size_t)blockIdx.x * 4 + (threadIdx.x >> 6);
  int lane = threadIdx.x & 63;
  const float4 x = *(const float4*)&ctx[row * SD + lane * 4];
  float s = x.x * x.x + x.y * x.y + x.z * x.z + x.w * x.w;
  #pragma unroll
  for (int m = 32; m >= 1; m >>= 1) s += __shfl_xor(s, m, 64);
  float rs = 1.0f / sqrtf(s * (1.0f / 256.0f) + 1e-6f);
  const float4 g = *(const float4*)&gate[row * SD + lane * 4];
  const float4 w = *(const float4*)&norm_w[lane * 4];
  ushort4 o;
  o.x = f2bf(x.x * rs * w.x * (g.x / (1.0f + expf(-g.x))));
  o.y = f2bf(x.y * rs * w.y * (g.y / (1.0f + expf(-g.y))));
  o.z = f2bf(x.z * rs * w.z * (g.z / (1.0f + expf(-g.z))));
  o.w = f2bf(x.w * rs * w.w * (g.w / (1.0f + expf(-g.w))));
  *(ushort4*)&ctx2[row * SD + lane * 4] = o;
}

// ---------------------------------------------------------------- output GEMM
__global__ void __launch_bounds__(256) out_gemm(
    const unsigned short* __restrict__ ctx2, const unsigned short* __restrict__ Wob,
    float* __restrict__ out)
{
  __shared__ unsigned short Asm[PM*PK];
  __shared__ unsigned short Bsm[PN*PK];
  const int t = threadIdx.x;
  const int w = t >> 6, lane = t & 63;
  const int bm0 = blockIdx.x * PM;
  const int bn0 = blockIdx.y * PN;

  f32x4 acc[2][4];
  #pragma unroll
  for (int i = 0; i < 2; ++i)
    #pragma unroll
    for (int j = 0; j < 4; ++j) acc[i][j] = (f32x4){0.f, 0.f, 0.f, 0.f};

  for (int k0 = 0; k0 < SD; k0 += PK) {
    #pragma unroll
    for (int it = 0; it < 4; ++it) {
      int unit = t + it * 256;
      int row = unit >> 3, seg = unit & 7;
      int dseg = seg ^ (row & 7);
      const unsigned short* g = ctx2 + (size_t)(bm0 + row) * SD + k0 + dseg * 8;
      gload16(g, (char*)Asm + (w * 1024 + it * 4096));
    }
    #pragma unroll
    for (int it = 0; it < 2; ++it) {
      int unit = t + it * 256;
      int n = unit >> 3, seg = unit & 7;
      int dseg = seg ^ (n & 7);
      const unsigned short* g = Wob + (size_t)(bn0 + n) * SD + k0 + dseg * 8;
      gload16(g, (char*)Bsm + (w * 1024 + it * 4096));
    }
    __syncthreads();
    #pragma unroll
    for (int ks = 0; ks < 2; ++ks) {
      short8 af[2], bfr[4];
      int u = ks * 4 + (lane >> 4);
      int slot = u ^ (lane & 7);
      #pragma unroll
      for (int rb = 0; rb < 2; ++rb) {
        int row = w * 32 + rb * 16 + (lane & 15);
        af[rb] = *(const short8*)((const char*)Asm + row * 128 + slot * 16);
      }
      #pragma unroll
      for (int cb = 0; cb < 4; ++cb) {
        int nn = cb * 16 + (lane & 15);
        bfr[cb] = *(const short8*)((const char*)Bsm + nn * 128 + slot * 16);
      }
      #pragma unroll
      for (int rb = 0; rb < 2; ++rb)
        #pragma unroll
        for (int cb = 0; cb < 4; ++cb)
          acc[rb][cb] = __builtin_amdgcn_mfma_f32_16x16x32_bf16(af[rb], bfr[cb], acc[rb][cb], 0, 0, 0);
    }
    __syncthreads();
  }
  #pragma unroll
  for (int rb = 0; rb < 2; ++rb)
    #pragma unroll
    for (int cb = 0; cb < 4; ++cb) {
      int n = bn0 + cb * 16 + (lane & 15);
      #pragma unroll
      for (int r = 0; r < 4; ++r) {
        int m = bm0 + w * 32 + rb * 16 + (lane >> 4) * 4 + r;
        out[(size_t)m * 512 + n] = acc[rb][cb][r];
      }
    }
}

// ---------------------------------------------------------------- launcher
// ws layout (bytes), total 253,493,248:
//   hb   bf16 [32768][512]            @ 0
//   Wc   bf16 [1536][512]             @ 33,554,432
//   Wob  bf16 [512][256]              @ 35,127,296
//   KQi  f32  [64][4096][64]          @ 35,389,440   (16 groups x [k2, q2])
//   AVB  f32x4 [64][4096][32]         @ 102,498,304  (a, v, beta, pad)
//   ctx2 bf16 [32768][256]            @ 236,716,032
// d_out reuse: ctx f32 [32768][256] @ 0; gate f32 [32768][256] @ +8388608 floats
// (both overwritten later by out_gemm); Sfin @ +16777216 floats.
extern "C" void kernel_launch(void* const* d_in, const int* in_sizes, int n_in,
                              void* d_out, int out_size, void* d_ws, size_t ws_size,
                              hipStream_t stream) {
  (void)in_sizes; (void)n_in; (void)out_size; (void)ws_size;
  const float* hidden  = (const float*)d_in[0];
  const float* state   = (const float*)d_in[1];
  const float* W_k     = (const float*)d_in[2];
  const float* W_v     = (const float*)d_in[3];
  const float* W_q     = (const float*)d_in[4];
  const float* W_beta  = (const float*)d_in[5];
  const float* b_beta  = (const float*)d_in[6];
  const float* W_alpha = (const float*)d_in[7];
  const float* b_alpha = (const float*)d_in[8];
  const float* W_out   = (const float*)d_in[9];
  const float* gate_W  = (const float*)d_in[10];
  const float* norm_w  = (const float*)d_in[11];
  float* out = (float*)d_out;

  char* ws = (char*)d_ws;
  unsigned short* hb  = (unsigned short*)(ws);
  unsigned short* Wc  = (unsigned short*)(ws + 33554432);
  unsigned short* Wob = (unsigned short*)(ws + 35127296);
  float* KQi  = (float*)(ws + 35389440);
  float* AVBf = (float*)(ws + 102498304);
  unsigned short* ctx2 = (unsigned short*)(ws + 236716032);
  float* ctx  = out;                 // fp32 scratch, overwritten by out_gemm
  float* gate = out + 8388608;       // fp32 scratch, overwritten by out_gemm
  float* Sfin = out + 16777216;      // final state output

  cvt_f32_bf16<<<2048, 256, 0, stream>>>(hidden, hb, M_TOK * HID / 4);
  cvt_weights<<<dim3(128, 7), 256, 0, stream>>>(W_k, W_v, W_q, W_beta, W_alpha, gate_W, W_out, Wc, Wob);

  proj_gemm<<<dim3(256, 8), 256, 0, stream>>>(hb, Wc, b_beta, b_alpha, KQi, AVBf, gate);
  scan_kernel<<<512, 64, 0, stream>>>(KQi, AVBf, state, ctx, Sfin);
  rms_silu<<<8192, 256, 0, stream>>>(ctx, gate, norm_w, ctx2);
  out_gemm<<<dim3(256, 8), 256, 0, stream>>>(ctx2, Wob, out);
}

// Round 16
// 399.160 us; speedup vs baseline: 1.4490x; 1.4490x over previous
//
#include <hip/hip_runtime.h>
#include <stdint.h>

// Problem constants
#define B_    8
#define T_    4096
#define HID   512
#define SD    256
#define NH    8
#define HD    32
#define M_TOK (B_*T_)          // 32768 tokens

typedef __attribute__((ext_vector_type(8))) short short8;   // 8 bf16 (4 VGPRs) — MFMA A/B frag
typedef __attribute__((ext_vector_type(4))) float f32x4;    // MFMA C/D frag
typedef __attribute__((ext_vector_type(4))) float f4;       // reg-tuple 4xf32 (asm-safe)
typedef __attribute__((ext_vector_type(2))) float f2;       // packed fp32 (v_pk_*_f32)

__device__ __forceinline__ unsigned short f2bf(float f) {
  uint32_t u = __float_as_uint(f);
  uint32_t r = (u + 0x7fffu + ((u >> 16) & 1u)) >> 16;
  return (unsigned short)r;
}

__device__ __forceinline__ void gload16(const void* g, void* l) {
  // async global->LDS, 16B per lane; LDS dest = wave-uniform base + lane*16
  __builtin_amdgcn_global_load_lds((const __attribute__((address_space(1))) void*)g,
                                   (__attribute__((address_space(3))) void*)l,
                                   16, 0, 0);
}

// butterfly sum across 16 consecutive lanes — pure VALU (DPP), no DS pipe.
__device__ __forceinline__ float qred16(float x) {
  x += __int_as_float(__builtin_amdgcn_mov_dpp(__float_as_int(x), 0xB1,  0xF, 0xF, true));
  x += __int_as_float(__builtin_amdgcn_mov_dpp(__float_as_int(x), 0x4E,  0xF, 0xF, true));
  x += __int_as_float(__builtin_amdgcn_mov_dpp(__float_as_int(x), 0x141, 0xF, 0xF, true));
  x += __int_as_float(__builtin_amdgcn_mov_dpp(__float_as_int(x), 0x128, 0xF, 0xF, true));
  return x;
}

// value of lane^1 (quad_perm [1,0,3,2]) — pure VALU
__device__ __forceinline__ float dpp_xor1(float x) {
  return __int_as_float(__builtin_amdgcn_mov_dpp(__float_as_int(x), 0xB1, 0xF, 0xF, true));
}

// ---------------------------------------------------------------- converts
__global__ void cvt_f32_bf16(const float* __restrict__ in, unsigned short* __restrict__ out, int n4) {
  int i = blockIdx.x * blockDim.x + threadIdx.x;
  int stride = gridDim.x * blockDim.x;
  for (; i < n4; i += stride) {
    float4 v = reinterpret_cast<const float4*>(in)[i];
    ushort4 o;
    o.x = f2bf(v.x); o.y = f2bf(v.y); o.z = f2bf(v.z); o.w = f2bf(v.w);
    reinterpret_cast<ushort4*>(out)[i] = o;
  }
}

// all 7 weight matrices in one launch: grid (128, 7), 32768 float4 per slice
__global__ void __launch_bounds__(256) cvt_weights(
    const float* __restrict__ W_k, const float* __restrict__ W_v,
    const float* __restrict__ W_q, const float* __restrict__ W_beta,
    const float* __restrict__ W_alpha, const float* __restrict__ gate_W,
    const float* __restrict__ W_out,
    unsigned short* __restrict__ Wc, unsigned short* __restrict__ Wob)
{
  int slice = blockIdx.y;
  const float* src = (slice == 0) ? W_k : (slice == 1) ? W_v : (slice == 2) ? W_q :
                     (slice == 3) ? W_beta : (slice == 4) ? W_alpha : (slice == 5) ? gate_W : W_out;
  unsigned short* dst = (slice == 6) ? Wob : (Wc + slice * 131072);
  int i = blockIdx.x * 256 + threadIdx.x;   // 0..32767 float4 units
  float4 v = reinterpret_cast<const float4*>(src)[i];
  ushort4 o;
  o.x = f2bf(v.x); o.y = f2bf(v.y); o.z = f2bf(v.z); o.w = f2bf(v.w);
  reinterpret_cast<ushort4*>(dst)[i] = o;
}

// ---------------------------------------------------------------- projection GEMM (fused 3-way)
// grid (256, 8): role 0-3: col-tile of {k, q, gate}; role 4-7: {alpha, v, beta}.
// KQi layout: [tok][16 groups g][k_{2g} k_{2g+1} q_{2g} q_{2g+1}] (16B/group).
// Epilogue writes FULL 16B groups per store (KQi via lane^1 DPP pair-exchange,
// even lanes store float4 {k0,k1,q0,q1}; AVB one float4 {a,v,b,0} per lane).
// k-normalization fused in-register (16-lane qred16 per token-half).
#define PM 128
#define PN 64
#define PK 64

__global__ void __launch_bounds__(256) proj_gemm(
    const unsigned short* __restrict__ hb, const unsigned short* __restrict__ Wc,
    const float* __restrict__ b_beta, const float* __restrict__ b_alpha,
    float* __restrict__ KQi, float* __restrict__ AVBf, float* __restrict__ gate)
{
  __shared__ unsigned short Asm[PM*PK];      // 16 KB
  __shared__ unsigned short Bsm[3][PN*PK];   // 24 KB
  const int t = threadIdx.x;
  const int w = t >> 6, lane = t & 63;
  const int bm0 = blockIdx.x * PM;
  const int role = blockIdx.y;
  const int grp = role >> 2;       // 0 = {k,q,gate}, 1 = {alpha,v,beta}
  const int bn0 = (role & 3) * 64; // column offset within each projection (0..255)
  const int pr0 = grp ? 4 : 0, pr1 = grp ? 1 : 2, pr2 = grp ? 3 : 5;

  f32x4 acc[3][2][4];
  #pragma unroll
  for (int pp = 0; pp < 3; ++pp)
    #pragma unroll
    for (int i = 0; i < 2; ++i)
      #pragma unroll
      for (int j = 0; j < 4; ++j) acc[pp][i][j] = (f32x4){0.f, 0.f, 0.f, 0.f};

  for (int k0 = 0; k0 < HID; k0 += PK) {
    #pragma unroll
    for (int it = 0; it < 4; ++it) {
      int unit = t + it * 256;
      int row = unit >> 3, seg = unit & 7;
      int dseg = seg ^ (row & 7);
      const unsigned short* g = hb + (size_t)(bm0 + row) * HID + k0 + dseg * 8;
      gload16(g, (char*)Asm + (w * 1024 + it * 4096));
    }
    #pragma unroll
    for (int pp = 0; pp < 3; ++pp) {
      const int pr = (pp == 0) ? pr0 : (pp == 1) ? pr1 : pr2;
      #pragma unroll
      for (int it = 0; it < 2; ++it) {
        int unit = t + it * 256;
        int n = unit >> 3, seg = unit & 7;
        int dseg = seg ^ (n & 7);
        const unsigned short* g = Wc + (size_t)(pr * 256 + bn0 + n) * HID + k0 + dseg * 8;
        gload16(g, (char*)Bsm[pp] + (w * 1024 + it * 4096));
      }
    }
    __syncthreads();
    #pragma unroll
    for (int ks = 0; ks < 2; ++ks) {
      short8 af[2];
      int u = ks * 4 + (lane >> 4);
      int slot = u ^ (lane & 7);
      #pragma unroll
      for (int rb = 0; rb < 2; ++rb) {
        int row = w * 32 + rb * 16 + (lane & 15);
        af[rb] = *(const short8*)((const char*)Asm + row * 128 + slot * 16);
      }
      #pragma unroll
      for (int pp = 0; pp < 3; ++pp) {
        short8 bfr[4];
        #pragma unroll
        for (int cb = 0; cb < 4; ++cb) {
          int nn = cb * 16 + (lane & 15);
          bfr[cb] = *(const short8*)((const char*)Bsm[pp] + nn * 128 + slot * 16);
        }
        #pragma unroll
        for (int rb = 0; rb < 2; ++rb)
          #pragma unroll
          for (int cb = 0; cb < 4; ++cb)
            acc[pp][rb][cb] = __builtin_amdgcn_mfma_f32_16x16x32_bf16(af[rb], bfr[cb], acc[pp][rb][cb], 0, 0, 0);
      }
    }
    __syncthreads();
  }

  if (grp == 0) {
    // fused k-normalization (16-lane DPP row covers all 32 d of one (m,h))
    #pragma unroll
    for (int rb = 0; rb < 2; ++rb) {
      #pragma unroll
      for (int r = 0; r < 4; ++r) {
        float s0 = acc[0][rb][0][r] * acc[0][rb][0][r] + acc[0][rb][1][r] * acc[0][rb][1][r];
        float s1 = acc[0][rb][2][r] * acc[0][rb][2][r] + acc[0][rb][3][r] * acc[0][rb][3][r];
        s0 = qred16(s0); s1 = qred16(s1);
        float i0 = 1.0f / fmaxf(sqrtf(s0), 1e-12f);
        float i1 = 1.0f / fmaxf(sqrtf(s1), 1e-12f);
        acc[0][rb][0][r] *= i0; acc[0][rb][1][r] *= i0;
        acc[0][rb][2][r] *= i1; acc[0][rb][3][r] *= i1;
      }
    }
    // even lanes write full KQi 16B group {k0,k1,q0,q1}
    #pragma unroll
    for (int rb = 0; rb < 2; ++rb) {
      #pragma unroll
      for (int cb = 0; cb < 4; ++cb) {
        int rem = bn0 + cb * 16 + (lane & 15);
        int h = rem >> 5, d = rem & 31;
        #pragma unroll
        for (int r = 0; r < 4; ++r) {
          int m = bm0 + w * 32 + rb * 16 + (lane >> 4) * 4 + r;
          int bb = m >> 12, tt = m & 4095;
          size_t tok = ((size_t)(bb * NH + h) * T_ + tt);
          float kv = acc[0][rb][cb][r], qv = acc[1][rb][cb][r];
          float kn = dpp_xor1(kv), qn = dpp_xor1(qv);
          if ((lane & 1) == 0)
            *(float4*)&KQi[tok * 64 + (d >> 1) * 4] = (float4){kv, kn, qv, qn};
          gate[(size_t)m * SD + rem] = acc[2][rb][cb][r];
        }
      }
    }
  } else {
    // one full 16B AVB group {alpha, v, beta, 0} per lane
    #pragma unroll
    for (int rb = 0; rb < 2; ++rb) {
      #pragma unroll
      for (int cb = 0; cb < 4; ++cb) {
        int rem = bn0 + cb * 16 + (lane & 15);
        int h = rem >> 5, d = rem & 31;
        #pragma unroll
        for (int r = 0; r < 4; ++r) {
          int m = bm0 + w * 32 + rb * 16 + (lane >> 4) * 4 + r;
          int bb = m >> 12, tt = m & 4095;
          size_t tok = ((size_t)(bb * NH + h) * T_ + tt);
          float av = 1.0f / (1.0f + expf(-(acc[0][rb][cb][r] + b_alpha[rem])));
          float vv = acc[1][rb][cb][r];
          float bv = 1.0f / (1.0f + expf(-(acc[2][rb][cb][r] + b_beta[rem])));
          *(float4*)&AVBf[(tok * HD + d) * 4] = (float4){av, vv, bv, 0.0f};
        }
      }
    }
  }
}

// ---------------------------------------------------------------- sequential scan
// 512 blocks x 128 threads (r14 structure + DEPTH-3 lgkm pipeline).
// block = (rg, bh): bh = blk&63, rg = blk>>6. WAVE0: lane = row il (lw>>4) x
// part p (lw&15), 2 state cols/lane. 2-step lookahead pairs; G = k_t.k_{t+1}
// from wave1 in the AVB pad word. Readout qred16s off-chain; lane-selected
// global dword store per 16 steps. Per pair: 4 ds_read_b128. DEPTH-3 pair-sets
// (A..F, 12 reads outstanding <= 15 lgkm cap): steady WKA2(8) fires ~2 pairs
// (~180cy) after the consumed reads issued > ~120cy DS round-trip -> waits
// ~free (r14's depth-2 WKA2(4) exposed ~60cy/pair). Tail 8/4/0 drains before
// each chunk BAR. WAVE1: stage chunk c+1 (global_load_lds) + G writes;
// vmcnt(0), gwrite, lgkm(0) before publishing BAR. 1 barrier per 32-step chunk.
// LDS: KQ dbuf 16KB @0, AVB dbuf 4KB @16384 = 20.5 KB.
#define CH 32
#define NCH (T_/CH)

#define DSR(dst, areg, imm) \
  asm volatile("ds_read_b128 %0, %1 offset:%c2" : "=v"(dst) : "v"(areg), "i"(imm))

#define SHUF2(V,A,B) __builtin_shufflevector(V, V, A, B)

#define BAR asm volatile("s_barrier" ::: "memory")

__global__ void __launch_bounds__(128, 1) scan_kernel(
    const float* __restrict__ KQi, const float4* __restrict__ AVB,
    const float* __restrict__ state_in,
    float* __restrict__ ctx, float* __restrict__ Sfin)
{
  __shared__ __align__(16) char Lds[20480];
  const int blk = blockIdx.x;
  const int bh = blk & 63, rg = blk >> 6;
  const int b = bh >> 3, h = bh & 7;
  const int tid = threadIdx.x;
  const int wid = tid >> 6;
  const int lw = tid & 63;

  const float*  KQg = KQi + (size_t)bh * (T_ * 64);
  const float4* Vg  = AVB + (size_t)bh * (T_ * HD) + rg * 4;

  const uint32_t lds0 = (uint32_t)(uintptr_t)(__attribute__((address_space(3))) char*)&Lds[0];

  if (wid == 1) {
    // ---------------- WAVE1: producer (staging + G) ----------------
    const int gpp = lw >> 2, gqt = lw & 3;   // pair 0..15, row 0..3
    f4 gx0, gx1, gx2, gx3, gy0, gy1, gy2, gy3;
    const uint32_t a_gw = lds0 + 16384 + (2 * gpp) * 64 + gqt * 16 + 12;

    auto stageW = [&](int c2, int buf) {
      const float* kqg = KQg + (size_t)c2 * (CH * 64);
      #pragma unroll
      for (int it = 0; it < 8; ++it)
        gload16(kqg + (size_t)(lw + it * 64) * 4, Lds + buf * 8192 + it * 1024);
      const float4* vg = Vg + (size_t)c2 * (CH * HD);
      #pragma unroll
      for (int it = 0; it < 2; ++it) {
        int tc = it * 16 + (lw >> 2), r = lw & 3;
        gload16(vg + (size_t)tc * HD + r, Lds + 16384 + buf * 2048 + it * 1024);
      }
    };

    auto gfetch = [&](int c2) {
      const float* gp = KQg + ((size_t)c2 * CH + 2 * gpp) * 64 + gqt * 16;
      gx0 = *(const f4*)(gp);      gx1 = *(const f4*)(gp + 4);
      gx2 = *(const f4*)(gp + 8);  gx3 = *(const f4*)(gp + 12);
      gy0 = *(const f4*)(gp + 64); gy1 = *(const f4*)(gp + 68);
      gy2 = *(const f4*)(gp + 72); gy3 = *(const f4*)(gp + 76);
    };

    auto gwrite = [&](int buf) {
      f2 g2 = SHUF2(gx0, 0, 1) * SHUF2(gy0, 0, 1);
      g2 = __builtin_elementwise_fma(SHUF2(gx1, 0, 1), SHUF2(gy1, 0, 1), g2);
      g2 = __builtin_elementwise_fma(SHUF2(gx2, 0, 1), SHUF2(gy2, 0, 1), g2);
      g2 = __builtin_elementwise_fma(SHUF2(gx3, 0, 1), SHUF2(gy3, 0, 1), g2);
      float G = g2.x + g2.y;
      G += __int_as_float(__builtin_amdgcn_mov_dpp(__float_as_int(G), 0xB1, 0xF, 0xF, true));
      G += __int_as_float(__builtin_amdgcn_mov_dpp(__float_as_int(G), 0x4E, 0xF, 0xF, true));
      uint32_t aw = a_gw + buf * 2048;
      asm volatile("ds_write_b32 %0, %1" :: "v"(aw), "v"(G));
      asm volatile("s_waitcnt lgkmcnt(0)" ::: "memory");   // G lands before BAR
    };

    gfetch(0);
    stageW(0, 0);
    asm volatile("s_waitcnt vmcnt(0)" ::: "memory");
    gwrite(0);
    BAR;   // prologue: chunk 0 staged + G in pads
    #pragma unroll 1
    for (int c = 0; c < NCH; ++c) {
      if (c + 1 < NCH) {
        gfetch(c + 1);
        stageW(c + 1, (c + 1) & 1);
        asm volatile("s_waitcnt vmcnt(0)" ::: "memory");
        gwrite((c + 1) & 1);
      }
      BAR;
    }
    return;
  }

  // ---------------- WAVE0: the sequential recurrence (2-step pairs) ----------------
  const int il = lw >> 4;    // local row
  const int p  = lw & 15;    // column part (cols 2p, 2p+1)

  f2 S2;
  {
    const float* sp = state_in + (size_t)bh * 1024 + (rg * 4 + il) * 32 + p * 2;
    S2 = (f2){sp[0], sp[1]};
  }

  const uint32_t a_kq = lds0 + p * 16;
  const uint32_t a_v  = lds0 + 16384 + il * 16;

  float osel = 0.0f;
  float* ctxp = ctx + (size_t)b * T_ * SD + (size_t)p * SD + h * HD + rg * 4 + il;

  f4 kqA, vvA, kqB, vvB, kqC, vvC, kqD, vvD, kqE, vvE, kqF, vvF;

#define R2(X, Y, BUF, J) do { \
    DSR(kq##X, a_kq, (BUF)*8192 + (2*(J))*256); \
    DSR(vv##X, a_v,  (BUF)*2048 + (2*(J))*64); \
    DSR(kq##Y, a_kq, (BUF)*8192 + (2*(J)+1)*256); \
    DSR(vv##Y, a_v,  (BUF)*2048 + (2*(J)+1)*64); \
  } while (0)

#define WKA2(N, X, Y) \
    asm volatile("s_waitcnt lgkmcnt(" #N ")" \
                 : "+v"(kq##X), "+v"(vv##X), "+v"(kq##Y), "+v"(vv##Y))

// pair compute: X holds even step T0 (with G in vv.w), Y holds T0+1.
// Readout qred16s are OFF the recurrence chain (ILP overlap).
#define C2(X, Y, T0) do { \
    f2 k0_ = SHUF2(kq##X, 0, 1), q0_ = SHUF2(kq##X, 2, 3); \
    f2 k1_ = SHUF2(kq##Y, 0, 1), q1_ = SHUF2(kq##Y, 2, 3); \
    f4 VA_ = vv##X, VB_ = vv##Y; \
    f2 dA_ = k0_ * S2, dB_ = k1_ * S2; \
    float W0_ = qred16(dA_.x + dA_.y); \
    float W1_ = qred16(dB_.x + dB_.y); \
    float u0_ = fmaf(-(VA_.z * VA_.x), W0_, VA_.z * VA_.y); \
    float bua_ = VB_.z * VB_.x; \
    float c2_ = bua_ * VA_.w; \
    float c1_ = fmaf(-(bua_ * VA_.x), W1_, VB_.z * VB_.y); \
    float u1_ = fmaf(-c2_, u0_, c1_); \
    f2 St_ = __builtin_elementwise_fma((f2){u0_, u0_}, k0_, (f2){VA_.x, VA_.x} * S2); \
    f2 Su_ = __builtin_elementwise_fma((f2){u1_, u1_}, k1_, (f2){VB_.x, VB_.x} * St_); \
    f2 o0_ = q0_ * St_; \
    f2 o1_ = q1_ * Su_; \
    S2 = Su_; \
    float od0_ = qred16(o0_.x + o0_.y); \
    float od1_ = qred16(o1_.x + o1_.y); \
    osel = (p == ((T0) & 15))       ? od0_ : osel; \
    osel = (p == (((T0) + 1) & 15)) ? od1_ : osel; \
    if ((((T0) + 1) & 15) == 15) { *ctxp = osel; ctxp += 16 * SD; } \
  } while (0)

// depth-3 rotation over sets (A,B) (C,D) (E,F); refills J=3..15.
#define CHUNK(BUF) do { \
    R2(A,B,BUF,0); R2(C,D,BUF,1); R2(E,F,BUF,2); \
    WKA2(8,A,B); C2(A,B, 0); R2(A,B,BUF,3); \
    WKA2(8,C,D); C2(C,D, 2); R2(C,D,BUF,4); \
    WKA2(8,E,F); C2(E,F, 4); R2(E,F,BUF,5); \
    WKA2(8,A,B); C2(A,B, 6); R2(A,B,BUF,6); \
    WKA2(8,C,D); C2(C,D, 8); R2(C,D,BUF,7); \
    WKA2(8,E,F); C2(E,F,10); R2(E,F,BUF,8); \
    WKA2(8,A,B); C2(A,B,12); R2(A,B,BUF,9); \
    WKA2(8,C,D); C2(C,D,14); R2(C,D,BUF,10); \
    WKA2(8,E,F); C2(E,F,16); R2(E,F,BUF,11); \
    WKA2(8,A,B); C2(A,B,18); R2(A,B,BUF,12); \
    WKA2(8,C,D); C2(C,D,20); R2(C,D,BUF,13); \
    WKA2(8,E,F); C2(E,F,22); R2(E,F,BUF,14); \
    WKA2(8,A,B); C2(A,B,24); R2(A,B,BUF,15); \
    WKA2(8,C,D); C2(C,D,26); \
    WKA2(4,E,F); C2(E,F,28); \
    WKA2(0,A,B); C2(A,B,30); \
    BAR; \
  } while (0)

  BAR;   // prologue: wait for wave1's stage(0)+G(0)
  #pragma unroll 1
  for (int cp = 0; cp < NCH / 2; ++cp) {
    CHUNK(0);
    CHUNK(1);
  }

  {
    float* sp = Sfin + (size_t)bh * 1024 + (rg * 4 + il) * 32 + p * 2;
    sp[0] = S2.x; sp[1] = S2.y;
  }
#undef C2
#undef R2
#undef WKA2
#undef CHUNK
}

// ---------------------------------------------------------------- rmsnorm * silu(gate) -> bf16
__global__ void __launch_bounds__(256) rms_silu(
    const float* __restrict__ ctx, const float* __restrict__ gate,
    const float* __restrict__ norm_w, unsigned short* __restrict__ ctx2)
{
  size_t row = (size_t)blockIdx.x * 4 + (threadIdx.x >> 6);
  int lane = threadIdx.x & 63;
  const float4 x = *(const float4*)&ctx[row * SD + lane * 4];
  float s = x.x * x.x + x.y * x.y + x.z * x.z + x.w * x.w;
  #pragma unroll
  for (int m = 32; m >= 1; m >>= 1) s += __shfl_xor(s, m, 64);
  float rs = 1.0f / sqrtf(s * (1.0f / 256.0f) + 1e-6f);
  const float4 g = *(const float4*)&gate[row * SD + lane * 4];
  const float4 w = *(const float4*)&norm_w[lane * 4];
  ushort4 o;
  o.x = f2bf(x.x * rs * w.x * (g.x / (1.0f + expf(-g.x))));
  o.y = f2bf(x.y * rs * w.y * (g.y / (1.0f + expf(-g.y))));
  o.z = f2bf(x.z * rs * w.z * (g.z / (1.0f + expf(-g.z))));
  o.w = f2bf(x.w * rs * w.w * (g.w / (1.0f + expf(-g.w))));
  *(ushort4*)&ctx2[row * SD + lane * 4] = o;
}

// ---------------------------------------------------------------- output GEMM
__global__ void __launch_bounds__(256) out_gemm(
    const unsigned short* __restrict__ ctx2, const unsigned short* __restrict__ Wob,
    float* __restrict__ out)
{
  __shared__ unsigned short Asm[PM*PK];
  __shared__ unsigned short Bsm[PN*PK];
  const int t = threadIdx.x;
  const int w = t >> 6, lane = t & 63;
  const int bm0 = blockIdx.x * PM;
  const int bn0 = blockIdx.y * PN;

  f32x4 acc[2][4];
  #pragma unroll
  for (int i = 0; i < 2; ++i)
    #pragma unroll
    for (int j = 0; j < 4; ++j) acc[i][j] = (f32x4){0.f, 0.f, 0.f, 0.f};

  for (int k0 = 0; k0 < SD; k0 += PK) {
    #pragma unroll
    for (int it = 0; it < 4; ++it) {
      int unit = t + it * 256;
      int row = unit >> 3, seg = unit & 7;
      int dseg = seg ^ (row & 7);
      const unsigned short* g = ctx2 + (size_t)(bm0 + row) * SD + k0 + dseg * 8;
      gload16(g, (char*)Asm + (w * 1024 + it * 4096));
    }
    #pragma unroll
    for (int it = 0; it < 2; ++it) {
      int unit = t + it * 256;
      int n = unit >> 3, seg = unit & 7;
      int dseg = seg ^ (n & 7);
      const unsigned short* g = Wob + (size_t)(bn0 + n) * SD + k0 + dseg * 8;
      gload16(g, (char*)Bsm + (w * 1024 + it * 4096));
    }
    __syncthreads();
    #pragma unroll
    for (int ks = 0; ks < 2; ++ks) {
      short8 af[2], bfr[4];
      int u = ks * 4 + (lane >> 4);
      int slot = u ^ (lane & 7);
      #pragma unroll
      for (int rb = 0; rb < 2; ++rb) {
        int row = w * 32 + rb * 16 + (lane & 15);
        af[rb] = *(const short8*)((const char*)Asm + row * 128 + slot * 16);
      }
      #pragma unroll
      for (int cb = 0; cb < 4; ++cb) {
        int nn = cb * 16 + (lane & 15);
        bfr[cb] = *(const short8*)((const char*)Bsm + nn * 128 + slot * 16);
      }
      #pragma unroll
      for (int rb = 0; rb < 2; ++rb)
        #pragma unroll
        for (int cb = 0; cb < 4; ++cb)
          acc[rb][cb] = __builtin_amdgcn_mfma_f32_16x16x32_bf16(af[rb], bfr[cb], acc[rb][cb], 0, 0, 0);
    }
    __syncthreads();
  }
  #pragma unroll
  for (int rb = 0; rb < 2; ++rb)
    #pragma unroll
    for (int cb = 0; cb < 4; ++cb) {
      int n = bn0 + cb * 16 + (lane & 15);
      #pragma unroll
      for (int r = 0; r < 4; ++r) {
        int m = bm0 + w * 32 + rb * 16 + (lane >> 4) * 4 + r;
        out[(size_t)m * 512 + n] = acc[rb][cb][r];
      }
    }
}

// ---------------------------------------------------------------- launcher
// ws layout (bytes), total 253,493,248:
//   hb   bf16 [32768][512]            @ 0
//   Wc   bf16 [1536][512]             @ 33,554,432
//   Wob  bf16 [512][256]              @ 35,127,296
//   KQi  f32  [64][4096][64]          @ 35,389,440   (16 groups x [k2, q2])
//   AVB  f32x4 [64][4096][32]         @ 102,498,304  (a, v, beta, pad/G)
//   ctx2 bf16 [32768][256]            @ 236,716,032
// d_out reuse: ctx f32 [32768][256] @ 0; gate f32 [32768][256] @ +8388608 floats
// (both overwritten later by out_gemm); Sfin @ +16777216 floats.
extern "C" void kernel_launch(void* const* d_in, const int* in_sizes, int n_in,
                              void* d_out, int out_size, void* d_ws, size_t ws_size,
                              hipStream_t stream) {
  (void)in_sizes; (void)n_in; (void)out_size; (void)ws_size;
  const float* hidden  = (const float*)d_in[0];
  const float* state   = (const float*)d_in[1];
  const float* W_k     = (const float*)d_in[2];
  const float* W_v     = (const float*)d_in[3];
  const float* W_q     = (const float*)d_in[4];
  const float* W_beta  = (const float*)d_in[5];
  const float* b_beta  = (const float*)d_in[6];
  const float* W_alpha = (const float*)d_in[7];
  const float* b_alpha = (const float*)d_in[8];
  const float* W_out   = (const float*)d_in[9];
  const float* gate_W  = (const float*)d_in[10];
  const float* norm_w  = (const float*)d_in[11];
  float* out = (float*)d_out;

  char* ws = (char*)d_ws;
  unsigned short* hb  = (unsigned short*)(ws);
  unsigned short* Wc  = (unsigned short*)(ws + 33554432);
  unsigned short* Wob = (unsigned short*)(ws + 35127296);
  float* KQi  = (float*)(ws + 35389440);
  float* AVBf = (float*)(ws + 102498304);
  unsigned short* ctx2 = (unsigned short*)(ws + 236716032);
  float* ctx  = out;                 // fp32 scratch, overwritten by out_gemm
  float* gate = out + 8388608;       // fp32 scratch, overwritten by out_gemm
  float* Sfin = out + 16777216;      // final state output

  cvt_f32_bf16<<<2048, 256, 0, stream>>>(hidden, hb, M_TOK * HID / 4);
  cvt_weights<<<dim3(128, 7), 256, 0, stream>>>(W_k, W_v, W_q, W_beta, W_alpha, gate_W, W_out, Wc, Wob);

  proj_gemm<<<dim3(256, 8), 256, 0, stream>>>(hb, Wc, b_beta, b_alpha, KQi, AVBf, gate);
  scan_kernel<<<512, 128, 0, stream>>>(KQi, (const float4*)AVBf, state, ctx, Sfin);
  rms_silu<<<8192, 256, 0, stream>>>(ctx, gate, norm_w, ctx2);
  out_gemm<<<dim3(256, 8), 256, 0, stream>>>(ctx2, Wob, out);
}